// Round 3
// baseline (170.908 us; speedup 1.0000x reference)
//
#include <hip/hip_runtime.h>

// out[b,s,d] = sum_hw feats[b,d,h,w] * masks[s,h,w]
// masks piecewise-constant on 3x3 rect grid (bands [0,9) [9,19) [19,28) both axes)
// => out[b,s,d] = sum_{r<9} w[s][r] * rectsum[b,d][r]

#define BLOCK 256
#define IMGS  64      // images (flat b*512+d) per block
#define HW    784
#define WD    28
#define NS    126
#define NR    9

// Accumulate rows [H0, H0+7) of one image into acc[9] (compile-time hband -> registers).
template<int H0>
__device__ __forceinline__ void rows7(const float* __restrict__ base, float* __restrict__ acc) {
    #pragma unroll
    for (int i = 0; i < 7; ++i) {
        const int h  = H0 + i;                       // unroll-constant
        const int hb = (h < 9) ? 0 : ((h < 19) ? 1 : 2);
        const float4* p = reinterpret_cast<const float4*>(base + h * WD);
        float4 v0 = p[0], v1 = p[1], v2 = p[2], v3 = p[3],
               v4 = p[4], v5 = p[5], v6 = p[6];
        // w bands: [0,9) [9,19) [19,28)
        float s0 = v0.x + v0.y + v0.z + v0.w + v1.x + v1.y + v1.z + v1.w + v2.x;
        float s1 = v2.y + v2.z + v2.w + v3.x + v3.y + v3.z + v3.w + v4.x + v4.y + v4.z;
        float s2 = v4.w + v5.x + v5.y + v5.z + v5.w + v6.x + v6.y + v6.z + v6.w;
        acc[hb * 3 + 0] += s0;
        acc[hb * 3 + 1] += s1;
        acc[hb * 3 + 2] += s2;
    }
}

__global__ __launch_bounds__(BLOCK, 4) void slots_kernel(
    const float* __restrict__ feats,
    const float* __restrict__ masks,
    float* __restrict__ out)
{
    __shared__ float rect4[4 * IMGS * NR];  // [q][g][r]
    __shared__ float rect_t[NR * IMGS];     // [r][g]: float4-readable per 4 channels
    __shared__ float wtab[NS * NR];         // 126 x 9 weights

    const int t        = threadIdx.x;
    const int img_base = blockIdx.x * IMGS;
    const int b        = img_base >> 9;     // / 512
    const int d0       = img_base & 511;

    const int g = t & 63;    // lane -> image
    const int q = t >> 6;    // wave -> row quarter (wave-uniform, no divergence)

    // ---- weight table (tiny; issue before the big streaming phase) ----
    for (int i = t; i < NS * NR; i += BLOCK) {
        const int s  = i / NR;
        const int r  = i - s * NR;
        const int bi = r / 3, bj = r - bi * 3;
        const int yc = (bi == 0) ? 4 : ((bi == 1) ? 14 : 23);
        const int xc = (bj == 0) ? 4 : ((bj == 1) ? 14 : 23);
        wtab[i] = masks[s * HW + yc * WD + xc];
    }

    // ---- Stage 1: register rect sums over this wave's 7 rows of image g ----
    float acc[NR] = {0.f, 0.f, 0.f, 0.f, 0.f, 0.f, 0.f, 0.f, 0.f};
    const float* base = feats + (size_t)(img_base + g) * HW;
    if      (q == 0) rows7<0 >(base, acc);
    else if (q == 1) rows7<7 >(base, acc);
    else if (q == 2) rows7<14>(base, acc);
    else             rows7<21>(base, acc);

    #pragma unroll
    for (int r = 0; r < NR; ++r)
        rect4[(q * IMGS + g) * NR + r] = acc[r];
    __syncthreads();

    // ---- Stage 2: reduce the 4 row-quarters; transpose to [r][g] ----
    // 576 tasks on 256 threads: MUST be a strided loop (R1 bug: plain if).
    for (int i = t; i < NR * IMGS; i += BLOCK) {
        const int r = i >> 6, gg = i & 63;
        rect_t[i] = rect4[(0 * IMGS + gg) * NR + r]
                  + rect4[(1 * IMGS + gg) * NR + r]
                  + rect4[(2 * IMGS + gg) * NR + r]
                  + rect4[(3 * IMGS + gg) * NR + r];
    }
    __syncthreads();

    // ---- Stage 3: 126 slots x 64 channels, float4 stores ----
    float* outb = out + (size_t)b * NS * 512 + d0;
    #pragma unroll
    for (int k = 0; k < 8; ++k) {
        const int i = t + k * BLOCK;
        if (i < (NS * IMGS) / 4) {               // 2016 float4 tasks
            const int s  = i >> 4;
            const int c4 = (i & 15) << 2;        // channel base (0..60)
            const float* wp = &wtab[s * NR];
            float4 a; a.x = a.y = a.z = a.w = 0.f;
            #pragma unroll
            for (int r = 0; r < NR; ++r) {
                const float4 rv = *reinterpret_cast<const float4*>(&rect_t[r * IMGS + c4]);
                const float  w  = wp[r];
                a.x += w * rv.x; a.y += w * rv.y; a.z += w * rv.z; a.w += w * rv.w;
            }
            *reinterpret_cast<float4*>(&outb[(size_t)s * 512 + c4]) = a;
        }
    }
}

extern "C" void kernel_launch(void* const* d_in, const int* in_sizes, int n_in,
                              void* d_out, int out_size, void* d_ws, size_t ws_size,
                              hipStream_t stream) {
    const float* feats = (const float*)d_in[0];   // (256, 512, 28, 28) f32
    const float* masks = (const float*)d_in[1];   // (126, 28, 28)      f32
    float* out = (float*)d_out;                   // (256, 126, 512)    f32

    const int blocks = (256 * 512) / IMGS;        // 2048
    slots_kernel<<<blocks, BLOCK, 0, stream>>>(feats, masks, out);
}

// Round 4
// 106.604 us; speedup vs baseline: 1.6032x; 1.6032x over previous
//
#include <hip/hip_runtime.h>

// out[b,s,d] = sum_hw feats[b,d,h,w] * masks[s,h,w]
// masks piecewise-constant on 3x3 rect grid (bands [0,9) [9,19) [19,28) both axes)
// => out[b,s,d] = sum_{r<9} w[s][r] * rectsum[b,d][r]
//
// R3: HBM loads are lane-linear float4 staging into LDS (structurally identical
// to the 6.29 TB/s copy ubench). Row = exactly 7 float4s -> flat f4 LDS layout
// needs no index math on writes and is bank-conflict-free on per-row reads
// ((7t+j) mod 8 distinct over any 8 consecutive lanes).

#define BLOCK 256
#define G     16            // images (flat b*512+d) per block
#define GC    8             // images per sub-chunk
#define F4C   (GC * 196)    // 1568 float4 per sub-chunk
#define NS    126
#define NR    9

__global__ void slots_kernel(
    const float* __restrict__ feats,
    const float* __restrict__ masks,
    float* __restrict__ out)
{
    __shared__ float4 buf[F4C];          // 25,088 B  staging (reused x2)
    __shared__ float  rs[G * 28 * 3];    //  5,376 B  per-row band sums
    __shared__ float  rect_t[NR * G];    //    576 B  [r][g]
    __shared__ float  wtab[NS * NR];     //  4,536 B

    const int t        = threadIdx.x;
    const int img_base = blockIdx.x * G;
    const int b        = img_base >> 9;     // / 512
    const int d0       = img_base & 511;

    // ---- weight table (overlaps with first staging) ----
    for (int i = t; i < NS * NR; i += BLOCK) {
        const int s  = i / NR;
        const int r  = i - s * NR;
        const int bi = r / 3, bj = r - bi * 3;
        const int yc = (bi == 0) ? 4 : ((bi == 1) ? 14 : 23);
        const int xc = (bj == 0) ? 4 : ((bj == 1) ? 14 : 23);
        wtab[i] = masks[s * 784 + yc * 28 + xc];
    }

    for (int c = 0; c < 2; ++c) {
        // ---- stage 8 images, lane-linear (perfectly coalesced) ----
        const float4* src = reinterpret_cast<const float4*>(feats)
                          + (size_t)(img_base + c * GC) * 196;
        #pragma unroll
        for (int k = 0; k < 6; ++k)
            buf[t + k * 256] = src[t + k * 256];
        if (t < 32)
            buf[t + 1536] = src[t + 1536];
        __syncthreads();

        // ---- per-row band sums from LDS (224 rows; conflict-free reads) ----
        if (t < GC * 28) {
            const float4* p = &buf[t * 7];
            float4 v0 = p[0], v1 = p[1], v2 = p[2], v3 = p[3],
                   v4 = p[4], v5 = p[5], v6 = p[6];
            float s0 = v0.x + v0.y + v0.z + v0.w + v1.x + v1.y + v1.z + v1.w + v2.x;
            float s1 = v2.y + v2.z + v2.w + v3.x + v3.y + v3.z + v3.w + v4.x + v4.y + v4.z;
            float s2 = v4.w + v5.x + v5.y + v5.z + v5.w + v6.x + v6.y + v6.z + v6.w;
            const int R = c * 224 + t;         // == g*28 + h globally
            rs[R * 3 + 0] = s0;
            rs[R * 3 + 1] = s1;
            rs[R * 3 + 2] = s2;
        }
        __syncthreads();   // protects buf reuse (c=1) and rs completeness
    }

    // ---- rect sums: 16 images x 9 rects ----
    if (t < G * NR) {
        const int g  = t / NR, r = t - g * NR;
        const int bi = r / 3, bj = r - bi * 3;
        const int h0 = (bi == 0) ? 0 : ((bi == 1) ? 9 : 19);
        const int h1 = (bi == 0) ? 9 : ((bi == 1) ? 19 : 28);
        float a = 0.f;
        for (int h = h0; h < h1; ++h)
            a += rs[(g * 28 + h) * 3 + bj];
        rect_t[r * G + g] = a;
    }
    __syncthreads();

    // ---- outputs: 126 slots x 16 channels, float4 stores ----
    float* outb = out + (size_t)b * NS * 512 + d0;
    for (int i = t; i < (NS * G) / 4; i += BLOCK) {   // 504 tasks
        const int s  = i >> 2;
        const int c4 = (i & 3) * 4;
        const float* wp = &wtab[s * NR];
        float4 a; a.x = a.y = a.z = a.w = 0.f;
        #pragma unroll
        for (int r = 0; r < NR; ++r) {
            const float  w  = wp[r];
            const float4 rv = *reinterpret_cast<const float4*>(&rect_t[r * G + c4]);
            a.x += w * rv.x; a.y += w * rv.y; a.z += w * rv.z; a.w += w * rv.w;
        }
        *reinterpret_cast<float4*>(&outb[(size_t)s * 512 + c4]) = a;
    }
}

extern "C" void kernel_launch(void* const* d_in, const int* in_sizes, int n_in,
                              void* d_out, int out_size, void* d_ws, size_t ws_size,
                              hipStream_t stream) {
    const float* feats = (const float*)d_in[0];   // (256, 512, 28, 28) f32
    const float* masks = (const float*)d_in[1];   // (126, 28, 28)      f32
    float* out = (float*)d_out;                   // (256, 126, 512)    f32

    const int blocks = (256 * 512) / G;           // 8192
    slots_kernel<<<blocks, BLOCK, 0, stream>>>(feats, masks, out);
}